// Round 4
// baseline (11471.812 us; speedup 1.0000x reference)
//
#include <hip/hip_runtime.h>
#include <hip/hip_bf16.h>

// Sizes (fixed by the problem)
#define S 4096
#define D 1024
#define H 1024
#define T 128
#define G4 4096   // 4*H gates

// ---------------------------------------------------------------------------
// init the h-communication ring (2 slots x H packed (tag<<32 | f32bits) u64)
// slot 1 holds h(-1) = 0 with tag 0 (readers of step t=0 accept immediately);
// slot 0 poisoned with an impossible tag.
__global__ void k_init(unsigned long long* hcomm) {
    int i = blockIdx.x * 256 + threadIdx.x;
    if (i < H) {
        hcomm[i]     = 0xFFFFFFFFFFFFFFFFull;  // slot 0: no valid tag
        hcomm[H + i] = 0ull;                   // slot 1: tag=0, h=0.0f
    }
}

// ---------------------------------------------------------------------------
// b_vo[j] = bo[j] + sum_k bv[k] * Wo[k,j]
__global__ void k_bvo(const float* __restrict__ Wo, const float* __restrict__ bv,
                      const float* __restrict__ bo, float* __restrict__ bvo) {
    int j = blockIdx.x * 256 + threadIdx.x;
    if (j >= D) return;
    float s = bo[j];
    for (int k = 0; k < D; ++k) s = fmaf(bv[k], Wo[k * D + j], s);
    bvo[j] = s;
}

// ---------------------------------------------------------------------------
// Build Wx (rows 0..1023 of [Wf|Wi|Wu|Wg], 1024 x 4096) and ball (4096)
__global__ void k_concat(const float* __restrict__ Wf, const float* __restrict__ Wi,
                         const float* __restrict__ Wu, const float* __restrict__ Wg,
                         const float* __restrict__ bf, const float* __restrict__ bi,
                         const float* __restrict__ bu, const float* __restrict__ bg,
                         float* __restrict__ Wx, float* __restrict__ ball) {
    int idx = blockIdx.x * 256 + threadIdx.x;       // 0 .. 1024*4096-1
    int k = idx >> 12;
    int col = idx & 4095;
    int g = col >> 10;
    int j = col & 1023;
    const float* W = (g == 0) ? Wf : (g == 1) ? Wi : (g == 2) ? Wu : Wg;
    Wx[idx] = W[k * D + j];   // x-part rows: 0..1023
    if (idx < G4) {
        const float* b = (g == 0) ? bf : (g == 1) ? bi : (g == 2) ? bu : bg;
        ball[idx] = b[j];
    }
}

// ---------------------------------------------------------------------------
// fp32 GEMM, 128x128 tile, 256 thr (4 waves as 2x2 of 64x64), 8x8 acc/thread.
// C[M,N] = Arows @ B + bias.  A row m is (gidx ? gidx[m] : m) of A.
// Requires M%128==0, N%128==0, K%16==0.
// LDS fragment reads: A-side is an 8-lane broadcast (conflict-free); B-side is
// 2-way (free, m136).  Inner loop: 64 FMA per 4 ds_read_b128 -> VALU-bound.
__global__ void __launch_bounds__(256) k_gemm128(
        const float* __restrict__ A, const float* __restrict__ B,
        const float* __restrict__ bias, const int* __restrict__ gidx,
        float* __restrict__ C, int M, int N, int K) {
    __shared__ float As[16][128];   // [kk][m]  (A staged transposed)
    __shared__ float Bs[16][128];   // [kk][n]
    const int tid = threadIdx.x;
    const int bm = blockIdx.y * 128, bn = blockIdx.x * 128;

    const int wave = tid >> 6, lane = tid & 63;
    const int wr = wave >> 1, wc = wave & 1;       // 2x2 wave grid
    const int lr = lane >> 3, lc = lane & 7;       // 8x8 lane grid
    const int row0 = wr * 64 + lr * 8;             // tile-local output rows
    const int col0 = wc * 64 + lc * 8;             // tile-local output cols

    // staging coords
    const int ra = tid >> 1;            // 0..127  A-tile row
    const int ca = (tid & 1) * 8;       // 0 / 8   A-tile col group
    const int rb = tid >> 4;            // 0..15   B-tile row
    const int cb = (tid & 15) * 8;      // 0..120  B-tile col group

    const long grow = gidx ? (long)gidx[bm + ra] : (long)(bm + ra);
    const float* Ap = A + (size_t)grow * K;
    const float* Bp = B + (size_t)bn + cb;

    float acc[8][8] = {};

    for (int kt = 0; kt < K; kt += 16) {
        float4 a0 = *reinterpret_cast<const float4*>(Ap + kt + ca);
        float4 a1 = *reinterpret_cast<const float4*>(Ap + kt + ca + 4);
        float4 bv0 = *reinterpret_cast<const float4*>(Bp + (size_t)(kt + rb) * N);
        float4 bv1 = *reinterpret_cast<const float4*>(Bp + (size_t)(kt + rb) * N + 4);
        As[ca + 0][ra] = a0.x; As[ca + 1][ra] = a0.y;
        As[ca + 2][ra] = a0.z; As[ca + 3][ra] = a0.w;
        As[ca + 4][ra] = a1.x; As[ca + 5][ra] = a1.y;
        As[ca + 6][ra] = a1.z; As[ca + 7][ra] = a1.w;
        *reinterpret_cast<float4*>(&Bs[rb][cb])     = bv0;
        *reinterpret_cast<float4*>(&Bs[rb][cb + 4]) = bv1;
        __syncthreads();
#pragma unroll
        for (int kk = 0; kk < 16; ++kk) {
            float a[8], b[8];
            *reinterpret_cast<float4*>(a)     = *reinterpret_cast<const float4*>(&As[kk][row0]);
            *reinterpret_cast<float4*>(a + 4) = *reinterpret_cast<const float4*>(&As[kk][row0 + 4]);
            *reinterpret_cast<float4*>(b)     = *reinterpret_cast<const float4*>(&Bs[kk][col0]);
            *reinterpret_cast<float4*>(b + 4) = *reinterpret_cast<const float4*>(&Bs[kk][col0 + 4]);
#pragma unroll
            for (int i = 0; i < 8; ++i)
#pragma unroll
                for (int j = 0; j < 8; ++j)
                    acc[i][j] = fmaf(a[i], b[j], acc[i][j]);
        }
        __syncthreads();
    }

    float bb[8];
#pragma unroll
    for (int j = 0; j < 8; ++j) bb[j] = bias ? bias[bn + col0 + j] : 0.f;

#pragma unroll
    for (int i = 0; i < 8; ++i) {
        float* Cp = C + (size_t)(bm + row0 + i) * N + bn + col0;
        float4 v0, v1;
        v0.x = acc[i][0] + bb[0]; v0.y = acc[i][1] + bb[1];
        v0.z = acc[i][2] + bb[2]; v0.w = acc[i][3] + bb[3];
        v1.x = acc[i][4] + bb[4]; v1.y = acc[i][5] + bb[5];
        v1.z = acc[i][6] + bb[6]; v1.w = acc[i][7] + bb[7];
        *reinterpret_cast<float4*>(Cp)     = v0;
        *reinterpret_cast<float4*>(Cp + 4) = v1;
    }
}

// ---------------------------------------------------------------------------
// Persistent cooperative LSTM — barrier-free dataflow version.
//
// 64 wgs x 1024 thr (16 waves).  wave w of wg owns output j = wg*16 + w.
// Within a wave: lane = g*16 + r  (g = gate 0..3; r = k mod 16).  Thread
// holds Wrec[k = r+16m][j] for m=0..63 in registers (64 wgs x 1024 thr x
// 64 fp32 = 16 MB: the whole recurrent matrix).
//
// Communication: h(t)[j] is published as ONE 8-byte agent-scope atomic
// (tag = t+1 high 32 bits, f32 bits low) into a 2-slot ring
// hcomm[(t&1)*H + j].  A consumer polls exactly hcomm[slot][tid] until the
// tag matches — the payload rides with the flag: no grid barrier, no
// arrival counters, no separate h reload.
//
// Ring safety: writing h(t+1) into slot (t+1)&1 requires having consumed
// ALL of h(t); h(t) complete means every wg finished step t, i.e. finished
// READING h(t-1) (the same slot).  So no slot is overwritten while any
// reader needs it; grid skew is bounded at 1 step.
__global__ void __launch_bounds__(1024, 4) k_lstm(
        const float* __restrict__ Wf, const float* __restrict__ Wi,
        const float* __restrict__ Wu, const float* __restrict__ Wg,
        const float* __restrict__ P, float* __restrict__ outs,
        unsigned long long* __restrict__ hcomm) {
    __shared__ float hx_lds[H];
    const int tid = threadIdx.x;
    const int wg = blockIdx.x;
    const int wave = tid >> 6;
    const int lane = tid & 63;
    const int g = lane >> 4;
    const int r = lane & 15;
    const int j = wg * 16 + wave;

    const float* Wsel = (g == 0) ? Wf : (g == 1) ? Wi : (g == 2) ? Wu : Wg;

    float wreg[64];
#pragma unroll
    for (int m = 0; m < 64; ++m)
        wreg[m] = Wsel[(size_t)(H + r + 16 * m) * D + j];   // recurrent rows 1024..2047

    float cx = 0.f;
    float pcur = (r == 0) ? P[(size_t)g * H + j] : 0.f;   // P row 0
    float pnext = 0.f;

    for (int t = 0; t < S; ++t) {
        // ---- poll my h(t-1) value straight out of the ring (payload==flag)
        {
            const unsigned long long want = (unsigned long long)t;  // tag of h(t-1)
            const int slot_r = (t - 1) & 1;                          // t=0 -> slot 1 (init)
            unsigned long long v;
            do {
                v = __hip_atomic_load(&hcomm[(size_t)slot_r * H + tid],
                                      __ATOMIC_RELAXED, __HIP_MEMORY_SCOPE_AGENT);
            } while ((v >> 32) != want);
            hx_lds[tid] = __uint_as_float((unsigned int)v);
        }
        __syncthreads();

        // ---- partial dot: k = r + 16m   (4 accumulators to break the chain)
        float s0 = 0.f, s1 = 0.f, s2 = 0.f, s3 = 0.f;
#pragma unroll
        for (int m = 0; m < 64; m += 4) {
            s0 = fmaf(wreg[m + 0], hx_lds[r + 16 * (m + 0)], s0);
            s1 = fmaf(wreg[m + 1], hx_lds[r + 16 * (m + 1)], s1);
            s2 = fmaf(wreg[m + 2], hx_lds[r + 16 * (m + 2)], s2);
            s3 = fmaf(wreg[m + 3], hx_lds[r + 16 * (m + 3)], s3);
        }
        float s = (s0 + s1) + (s2 + s3);

        // reduce over the 16 lanes of this (j,gate) column
        s += __shfl_xor(s, 1);
        s += __shfl_xor(s, 2);
        s += __shfl_xor(s, 4);
        s += __shfl_xor(s, 8);
        if (r == 0) s += pcur;

        // gather the 4 gate values (lanes 0,16,32,48) to every lane
        float fg = __shfl(s, 0);
        float ig = __shfl(s, 16);
        float gg = __shfl(s, 32);
        float og = __shfl(s, 48);

        float f_ = 1.f / (1.f + __expf(-fg));
        float i_ = 1.f / (1.f + __expf(-ig));
        float g_ = tanhf(gg);
        float o_ = 1.f / (1.f + __expf(-og));
        cx = f_ * cx + i_ * g_;
        float h = o_ * tanhf(cx);

        if (lane == 0) {
            // publish (tag,h) atomically into the ring + plain store for logits
            unsigned long long pk = ((unsigned long long)(t + 1) << 32) |
                                    (unsigned long long)__float_as_uint(h);
            __hip_atomic_store(&hcomm[(size_t)(t & 1) * H + j], pk,
                               __ATOMIC_RELAXED, __HIP_MEMORY_SCOPE_AGENT);
            outs[(size_t)t * H + j] = h;
        }

        // prefetch next P value (hides L3/HBM latency under the next poll)
        if (r == 0 && t + 1 < S)
            pnext = P[(size_t)(t + 1) * G4 + g * H + j];

        __syncthreads();   // hx_lds stable until all waves consumed it
        pcur = pnext;
    }
}

// ---------------------------------------------------------------------------
// logits = outs @ Wt + bt ; out = log_softmax(logits, axis=1)
__global__ void __launch_bounds__(128) k_logits(
        const float* __restrict__ outs, const float* __restrict__ Wt,
        const float* __restrict__ bt, float* __restrict__ out) {
    __shared__ float row[H];
    __shared__ float red[2];
    int srow = blockIdx.x;
    int t = threadIdx.x;          // 0..127
    for (int i = t; i < H; i += 128) row[i] = outs[(size_t)srow * H + i];
    __syncthreads();

    float acc = bt[t];
    for (int k = 0; k < H; ++k) acc = fmaf(row[k], Wt[k * T + t], acc);

    // block max (2 waves)
    float m = acc;
#pragma unroll
    for (int d = 1; d < 64; d <<= 1) m = fmaxf(m, __shfl_xor(m, d));
    if ((t & 63) == 0) red[t >> 6] = m;
    __syncthreads();
    m = fmaxf(red[0], red[1]);

    float e = __expf(acc - m);
    float sum = e;
#pragma unroll
    for (int d = 1; d < 64; d <<= 1) sum += __shfl_xor(sum, d);
    if ((t & 63) == 0) red[t >> 6] = sum;
    __syncthreads();
    sum = red[0] + red[1];

    out[(size_t)srow * T + t] = (acc - m) - logf(sum);
}

// ---------------------------------------------------------------------------
extern "C" void kernel_launch(void* const* d_in, const int* in_sizes, int n_in,
                              void* d_out, int out_size, void* d_ws, size_t ws_size,
                              hipStream_t stream) {
    (void)in_sizes; (void)n_in; (void)out_size; (void)ws_size;

    const int*   sentence = (const int*)  d_in[0];
    const float* emb      = (const float*)d_in[1];
    // d_in[2..5] = Wq,bq,Wk,bk  -> provably dead (softmax over singleton axis)
    const float* Wv = (const float*)d_in[6];
    const float* bv = (const float*)d_in[7];
    const float* Wo = (const float*)d_in[8];
    const float* bo = (const float*)d_in[9];
    const float* Wf = (const float*)d_in[10];
    const float* bf = (const float*)d_in[11];
    const float* Wi = (const float*)d_in[12];
    const float* bi = (const float*)d_in[13];
    const float* Wu = (const float*)d_in[14];
    const float* bu = (const float*)d_in[15];
    const float* Wg = (const float*)d_in[16];
    const float* bg = (const float*)d_in[17];
    const float* Wt = (const float*)d_in[18];
    const float* bt = (const float*)d_in[19];
    float* out = (float*)d_out;

    // workspace layout (floats; every block is a multiple of 1024 floats)
    float* ws    = (float*)d_ws;
    float* W_vo  = ws;                       // 1024*1024
    float* Wx    = W_vo + 1024 * 1024;       // 1024*4096
    float* attn  = Wx   + 1024 * 4096;       // 4096*1024
    float* P     = attn + 4096 * 1024;       // 4096*4096
    float* outs  = P    + (size_t)4096 * 4096; // 4096*1024
    float* bvo   = outs + 4096 * 1024;       // 1024
    float* ball  = bvo  + 1024;              // 4096
    unsigned long long* hcomm = (unsigned long long*)(ball + 4096); // 2*1024 u64

    k_init<<<4, 256, 0, stream>>>(hcomm);
    k_bvo<<<4, 256, 0, stream>>>(Wo, bv, bo, bvo);
    k_concat<<<(1024 * 4096) / 256, 256, 0, stream>>>(Wf, Wi, Wu, Wg,
                                                      bf, bi, bu, bg, Wx, ball);

    // W_vo = Wv @ Wo                      (M=N=K=1024)
    k_gemm128<<<dim3(8, 8), 256, 0, stream>>>(Wv, Wo, nullptr, nullptr,
                                              W_vo, 1024, 1024, 1024);
    // attn = emb[sentence] @ W_vo + bvo   (M=4096, N=1024, K=1024)
    k_gemm128<<<dim3(8, 32), 256, 0, stream>>>(emb, W_vo, bvo, sentence,
                                               attn, 4096, 1024, 1024);
    // P = attn @ Wx + ball                (M=4096, N=4096, K=1024)
    k_gemm128<<<dim3(32, 32), 256, 0, stream>>>(attn, Wx, ball, nullptr,
                                                P, 4096, 4096, 1024);

    // LSTM recurrence (cooperative: co-residency of all 64 wgs required)
    {
        void* args[] = { (void*)&Wf, (void*)&Wi, (void*)&Wu, (void*)&Wg,
                         (void*)&P, (void*)&outs, (void*)&hcomm };
        hipLaunchCooperativeKernel((void*)k_lstm, dim3(64), dim3(1024),
                                   args, 0, stream);
    }

    // logits + log_softmax
    k_logits<<<4096, 128, 0, stream>>>(outs, Wt, bt, out);
}